// Round 2
// baseline (393.658 us; speedup 1.0000x reference)
//
#include <hip/hip_runtime.h>

#define N_NODES 307
#define T_LEN   6000
#define L1      5991
#define L2      5982
#define ED      96
#define FDIM    95712
#define K5CH    187   // K chunks of 512 rows

// ---- workspace layout (float offsets) ----
// consts: [0..7]=s1 [8..15]=t1 [16..31]=s2 [32..47]=t2
static const size_t WS_P1 = 256;                    // conv1 stat partials: 375*16
static const size_t WS_P2 = 8192;                   // conv2 stat partials: 3740*32 = 119680
static const size_t WS_NF = 131072;                 // node_feat: 307*96
static const size_t WS_SP = 196608;                 // s_proj: 307*96
static const size_t WS_RP = 229376;                 // r_proj: 307*96
static const size_t WS_A2 = 262144;                 // a2: 95712*320 = 30,627,840
static const size_t WS_FP = 262144 + 30627840ull;   // fc partials: 187*96*320 = 5,744,640
// total ~= 146.5 MB

// ================= K1: conv1 + relu, channel stats only =================
__global__ __launch_bounds__(320) void dgl_k1_conv1_stats(
    const float* __restrict__ nfeat, const float* __restrict__ w1,
    const float* __restrict__ b1, float* __restrict__ ws) {
  __shared__ float sw1[80], sb1[8];
  __shared__ float sred[5][16];
  int tid = threadIdx.x;
  if (tid < 80) sw1[tid] = w1[tid];
  if (tid < 8)  sb1[tid] = b1[tid];
  __syncthreads();
  int l0 = blockIdx.x * 16;
  int n = tid;
  bool nv = n < N_NODES;
  float xx[26];
#pragma unroll
  for (int j = 0; j < 26; ++j) {
    int t = l0 + j;
    xx[j] = (nv && t < T_LEN) ? nfeat[(size_t)t * N_NODES + n] : 0.f;
  }
  float s[8], q[8];
#pragma unroll
  for (int c = 0; c < 8; ++c) { s[c] = 0.f; q[c] = 0.f; }
#pragma unroll
  for (int dl = 0; dl < 16; ++dl) {
    int l = l0 + dl;
    if (nv && l < L1) {
#pragma unroll
      for (int c = 0; c < 8; ++c) {
        float r = sb1[c];
#pragma unroll
        for (int k = 0; k < 10; ++k) r = fmaf(xx[dl + k], sw1[c * 10 + k], r);
        float z = fmaxf(r, 0.f);
        s[c] += z; q[c] += z * z;
      }
    }
  }
  int wv = tid >> 6, ln = tid & 63;
#pragma unroll
  for (int c = 0; c < 8; ++c) {
    float vs = s[c], vq = q[c];
    for (int o = 32; o; o >>= 1) { vs += __shfl_down(vs, o, 64); vq += __shfl_down(vq, o, 64); }
    if (ln == 0) { sred[wv][c] = vs; sred[wv][8 + c] = vq; }
  }
  __syncthreads();
  if (tid < 16) {
    float t = 0.f;
    for (int w = 0; w < 5; ++w) t += sred[w][tid];
    ws[WS_P1 + (size_t)blockIdx.x * 16 + tid] = t;
  }
}

// ================= K2: finalize bn1 =================
__global__ void dgl_k2_fin1(const float* __restrict__ g1, const float* __restrict__ b1,
                            float* __restrict__ ws) {
  __shared__ double sd[16];
  int tid = threadIdx.x;
  if (tid < 16) {
    double a = 0.0;
    for (int j = 0; j < 375; ++j) a += (double)ws[WS_P1 + (size_t)j * 16 + tid];
    sd[tid] = a;
  }
  __syncthreads();
  if (tid < 8) {
    double cnt = (double)N_NODES * (double)L1;
    double m = sd[tid] / cnt;
    double v = sd[tid + 8] / cnt - m * m;
    double inv = 1.0 / sqrt(v + 1e-5);
    ws[tid]     = (float)((double)g1[tid] * inv);
    ws[8 + tid] = (float)((double)b1[tid] - (double)g1[tid] * inv * m);
  }
}

// ================= K3: fused conv1+bn1 (recompute) -> conv2 + relu -> a2 + stats =================
__global__ __launch_bounds__(256) void dgl_k3_conv2(
    const float* __restrict__ nfeat, const float* __restrict__ w1, const float* __restrict__ b1,
    const float* __restrict__ w2, const float* __restrict__ b2, float* __restrict__ ws) {
  __shared__ float sx[26][64];
  __shared__ float sz[8][17][64];
  __shared__ float sw2[1280], sw1[80], sb1[8], sb2[16], ss1[8], st1[8];
  __shared__ float wpart[4][8];
  int tid = threadIdx.x;
  int lane = tid & 63, g = tid >> 6;
  int l0 = blockIdx.x * 8, n0 = blockIdx.y * 64;
  for (int i = tid; i < 1280; i += 256) sw2[i] = w2[i];
  if (tid < 80) sw1[tid] = w1[tid];
  if (tid < 8)  { sb1[tid] = b1[tid]; ss1[tid] = ws[tid]; st1[tid] = ws[8 + tid]; }
  if (tid < 16) sb2[tid] = b2[tid];
  for (int i = tid; i < 26 * 64; i += 256) {
    int j = i >> 6, l2 = i & 63;
    int t = l0 + j, nn = n0 + l2;
    sx[j][l2] = (t < T_LEN && nn < N_NODES) ? nfeat[(size_t)t * N_NODES + nn] : 0.f;
  }
  __syncthreads();
#pragma unroll
  for (int i = 0; i < 34; ++i) {
    int c = g * 2 + i / 17, lz = i % 17;
    float r = sb1[c];
#pragma unroll
    for (int k = 0; k < 10; ++k) r = fmaf(sx[lz + k][lane], sw1[c * 10 + k], r);
    sz[c][lz][lane] = fmaf(ss1[c], fmaxf(r, 0.f), st1[c]);
  }
  __syncthreads();
  float acc[4][8];
#pragma unroll
  for (int qq = 0; qq < 4; ++qq)
#pragma unroll
    for (int dl = 0; dl < 8; ++dl) acc[qq][dl] = 0.f;
  for (int c = 0; c < 8; ++c) {
    float zr[17];
#pragma unroll
    for (int t = 0; t < 17; ++t) zr[t] = sz[c][t][lane];
#pragma unroll
    for (int k = 0; k < 10; ++k) {
#pragma unroll
      for (int qq = 0; qq < 4; ++qq) {
        float w = sw2[(g * 4 + qq) * 80 + c * 10 + k];
#pragma unroll
        for (int dl = 0; dl < 8; ++dl) acc[qq][dl] = fmaf(zr[dl + k], w, acc[qq][dl]);
      }
    }
  }
  int n = n0 + lane;
  bool nv = n < N_NODES;
  float s4[4] = {0.f, 0.f, 0.f, 0.f}, q4[4] = {0.f, 0.f, 0.f, 0.f};
#pragma unroll
  for (int qq = 0; qq < 4; ++qq) {
    int c2 = g * 4 + qq;
#pragma unroll
    for (int dl = 0; dl < 8; ++dl) {
      int l = l0 + dl;
      float v = 0.f;
      if (nv && l < L2) v = fmaxf(acc[qq][dl] + sb2[c2], 0.f);
      if (l < L2) ws[WS_A2 + ((size_t)c2 * L2 + l) * 320 + n] = v;
      s4[qq] += v; q4[qq] += v * v;
    }
  }
#pragma unroll
  for (int qq = 0; qq < 4; ++qq) {
    float vs = s4[qq], vq = q4[qq];
    for (int o = 32; o; o >>= 1) { vs += __shfl_down(vs, o, 64); vq += __shfl_down(vq, o, 64); }
    if (lane == 0) { wpart[g][qq] = vs; wpart[g][4 + qq] = vq; }
  }
  __syncthreads();
  if (tid < 32) {
    int c2 = tid & 15; bool isq = tid >= 16;
    float v = wpart[c2 >> 2][(isq ? 4 : 0) + (c2 & 3)];
    ws[WS_P2 + ((size_t)blockIdx.y * gridDim.x + blockIdx.x) * 32 + tid] = v;
  }
}

// ================= K4: finalize bn2 =================
__global__ __launch_bounds__(512) void dgl_k4_fin2(const float* __restrict__ g2,
                                                   const float* __restrict__ b2,
                                                   float* __restrict__ ws) {
  __shared__ double dd[32][17];
  int tid = threadIdx.x;
  int v = tid >> 4, p = tid & 15;
  double a = 0.0;
  for (int j = p; j < 3740; j += 16) a += (double)ws[WS_P2 + (size_t)j * 32 + v];
  dd[v][p] = a;
  __syncthreads();
  if (tid < 32) {
    double s = 0.0;
    for (int pp = 0; pp < 16; ++pp) s += dd[tid][pp];
    dd[tid][16] = s;
  }
  __syncthreads();
  if (tid < 16) {
    double cnt = (double)N_NODES * (double)L2;
    double m = dd[tid][16] / cnt;
    double var = dd[tid + 16][16] / cnt - m * m;
    double inv = 1.0 / sqrt(var + 1e-5);
    ws[16 + tid] = (float)((double)g2[tid] * inv);
    ws[32 + tid] = (float)((double)b2[tid] - (double)g2[tid] * inv * m);
  }
}

// ================= K5: split-K GEMM, double-buffered, 1 chunk (512 rows) per block =================
__global__ __launch_bounds__(192) void dgl_k5_fc(const float* __restrict__ fcw,
                                                 float* __restrict__ ws) {
  __shared__ float As[2][16][68];
  __shared__ float Bs[2][16][100];
  __shared__ float s2s[16], t2s[16];
  int tid = threadIdx.x;
  if (tid < 16) { s2s[tid] = ws[16 + tid]; t2s[tid] = ws[32 + tid]; }
  __syncthreads();
  int tn = tid / 24, te = tid % 24;      // thread tile: 8n x 4e
  int ch = blockIdx.x;
  int n0 = blockIdx.y * 64;
  const float* a2 = ws + WS_A2;
  int fb0 = ch * 512;

  float acc[8][4];
#pragma unroll
  for (int i = 0; i < 8; ++i)
#pragma unroll
    for (int j = 0; j < 4; ++j) acc[i][j] = 0.f;

  // register staging slots
  float4 va0, va1, vb0, vb1;
  float sa0 = 0.f, ha0 = 0.f, sa1 = 0.f, ha1 = 0.f;
  int ar0 = tid >> 4, ac0 = tid & 15;          // A rows 0..11
  int ar1 = 12 + (tid >> 4), ac1 = tid & 15;   // A rows 12..15 (tid<64)
  bool has1 = tid < 64;

#define K5_PREF(KS) do {                                                        \
    int fbase = fb0 + (KS) * 16;                                                \
    { int f = fbase + ar0;                                                      \
      if (f < FDIM) { va0 = *(const float4*)(a2 + (size_t)f * 320 + n0 + ac0 * 4); \
        int cc = f / L2; sa0 = s2s[cc]; ha0 = t2s[cc]; }                        \
      else { va0 = make_float4(0.f,0.f,0.f,0.f); sa0 = 0.f; ha0 = 0.f; } }      \
    if (has1) { int f = fbase + ar1;                                            \
      if (f < FDIM) { va1 = *(const float4*)(a2 + (size_t)f * 320 + n0 + ac1 * 4); \
        int cc = f / L2; sa1 = s2s[cc]; ha1 = t2s[cc]; }                        \
      else { va1 = make_float4(0.f,0.f,0.f,0.f); sa1 = 0.f; ha1 = 0.f; } }      \
    { int f = fbase + tn;                                                       \
      vb0 = (f < FDIM) ? *(const float4*)(fcw + (size_t)f * 96 + te * 4)        \
                       : make_float4(0.f,0.f,0.f,0.f); }                        \
    { int f = fbase + tn + 8;                                                   \
      vb1 = (f < FDIM) ? *(const float4*)(fcw + (size_t)f * 96 + te * 4)        \
                       : make_float4(0.f,0.f,0.f,0.f); }                        \
  } while (0)

#define K5_WRITE(BUF) do {                                                      \
    float4 o;                                                                   \
    o.x = fmaf(sa0, va0.x, ha0); o.y = fmaf(sa0, va0.y, ha0);                   \
    o.z = fmaf(sa0, va0.z, ha0); o.w = fmaf(sa0, va0.w, ha0);                   \
    *(float4*)(&As[BUF][ar0][ac0 * 4]) = o;                                     \
    if (has1) {                                                                 \
      o.x = fmaf(sa1, va1.x, ha1); o.y = fmaf(sa1, va1.y, ha1);                 \
      o.z = fmaf(sa1, va1.z, ha1); o.w = fmaf(sa1, va1.w, ha1);                 \
      *(float4*)(&As[BUF][ar1][ac1 * 4]) = o; }                                 \
    *(float4*)(&Bs[BUF][tn][te * 4]) = vb0;                                     \
    *(float4*)(&Bs[BUF][tn + 8][te * 4]) = vb1;                                 \
  } while (0)

  K5_PREF(0);
  K5_WRITE(0);
  __syncthreads();
  int cur = 0;
  for (int ks = 0; ks < 32; ++ks) {
    if (ks < 31) K5_PREF(ks + 1);
#pragma unroll
    for (int kk = 0; kk < 16; ++kk) {
      float a[8], b[4];
      *(float4*)(a)     = *(float4*)(&As[cur][kk][tn * 8]);
      *(float4*)(a + 4) = *(float4*)(&As[cur][kk][tn * 8 + 4]);
      *(float4*)(b)     = *(float4*)(&Bs[cur][kk][te * 4]);
#pragma unroll
      for (int i = 0; i < 8; ++i)
#pragma unroll
        for (int j = 0; j < 4; ++j) acc[i][j] = fmaf(a[i], b[j], acc[i][j]);
    }
    if (ks < 31) {
      K5_WRITE(cur ^ 1);
      __syncthreads();
      cur ^= 1;
    }
  }
  float* fp = ws + WS_FP;
#pragma unroll
  for (int j = 0; j < 4; ++j) {
    int e = te * 4 + j;
    size_t base = ((size_t)ch * 96 + e) * 320 + n0 + tn * 8;
    float4 o1 = {acc[0][j], acc[1][j], acc[2][j], acc[3][j]};
    float4 o2 = {acc[4][j], acc[5][j], acc[6][j], acc[7][j]};
    *(float4*)(fp + base) = o1;
    *(float4*)(fp + base + 4) = o2;
  }
}

// ================= K6: chunk-reduce (fp64) + fc bias + relu + bn3 -> node_feat =================
__global__ __launch_bounds__(320) void dgl_k6_bn3(const float* __restrict__ fcb,
                                                  const float* __restrict__ g3,
                                                  const float* __restrict__ b3,
                                                  float* __restrict__ ws) {
  int e = blockIdx.x, tid = threadIdx.x;
  const float* fp = ws + WS_FP;
  double a = 0.0;
  for (int ch = 0; ch < K5CH; ++ch) a += (double)fp[((size_t)ch * 96 + e) * 320 + tid];
  float x = fmaxf((float)a + fcb[e], 0.f);
  if (tid >= N_NODES) x = 0.f;
  double s = (double)x, q = (double)x * (double)x;
  __shared__ double rs[5], rq[5];
  __shared__ float mb[2];
  int wv = tid >> 6, ln = tid & 63;
  for (int o = 32; o; o >>= 1) { s += __shfl_down(s, o, 64); q += __shfl_down(q, o, 64); }
  if (ln == 0) { rs[wv] = s; rq[wv] = q; }
  __syncthreads();
  if (tid == 0) {
    double S = 0.0, Q = 0.0;
    for (int w = 0; w < 5; ++w) { S += rs[w]; Q += rq[w]; }
    double m = S / (double)N_NODES;
    double var = Q / (double)N_NODES - m * m;
    mb[0] = (float)m; mb[1] = (float)(1.0 / sqrt(var + 1e-5));
  }
  __syncthreads();
  if (tid < N_NODES)
    ws[WS_NF + (size_t)tid * 96 + e] = g3[e] * (x - mb[0]) * mb[1] + b3[e];
}

// ================= K7: s_proj / r_proj =================
__global__ __launch_bounds__(192) void dgl_k7_proj(const float* __restrict__ fow,
                                                   float* __restrict__ ws) {
  __shared__ float sh[96];
  int nI = blockIdx.x, tid = threadIdx.x;
  if (tid < 96) sh[tid] = ws[WS_NF + (size_t)nI * 96 + tid];
  __syncthreads();
  int col = tid % 96, half = tid / 96;
  float a = 0.f;
#pragma unroll 8
  for (int d = 0; d < 96; ++d) a = fmaf(sh[d], fow[(size_t)(half * 96 + d) * 96 + col], a);
  ws[(half ? WS_RP : WS_SP) + (size_t)nI * 96 + col] = a;
}

// ================= K8: edge relu + logits + gumbel + hard argmax -> adj =================
__global__ __launch_bounds__(256) void dgl_k8_edge(const float* __restrict__ fob,
                                                   const float* __restrict__ fcatw,
                                                   const float* __restrict__ fcatb,
                                                   const float* __restrict__ unif,
                                                   const float* __restrict__ ws,
                                                   float* __restrict__ out) {
  __shared__ float rp[16][100], sp[16][100], bb[96], wa[96], wb[96];
  int tid = threadIdx.x;
  int i0 = blockIdx.y * 16, j0 = blockIdx.x * 16;
  for (int idx = tid; idx < 16 * 96; idx += 256) {
    int r = idx / 96, e = idx % 96;
    int ii = i0 + r, jj = j0 + r;
    rp[r][e] = (ii < N_NODES) ? ws[WS_RP + (size_t)ii * 96 + e] : 0.f;
    sp[r][e] = (jj < N_NODES) ? ws[WS_SP + (size_t)jj * 96 + e] : 0.f;
  }
  if (tid < 96) { bb[tid] = fob[tid]; wa[tid] = fcatw[2 * tid]; wb[tid] = fcatw[2 * tid + 1]; }
  __syncthreads();
  int il = tid >> 4, jl = tid & 15;
  int i = i0 + il, j = j0 + jl;
  float a0 = 0.f, a1 = 0.f;
#pragma unroll 4
  for (int e = 0; e < 96; ++e) {
    float ef = fmaxf(rp[il][e] + sp[jl][e] + bb[e], 0.f);
    a0 = fmaf(ef, wa[e], a0);
    a1 = fmaf(ef, wb[e], a1);
  }
  if (i < N_NODES && j < N_NODES) {
    size_t ue = ((size_t)i * N_NODES + j) * 2;
    float g0 = -logf(-logf(unif[ue] + 1e-20f) + 1e-20f);
    float g1 = -logf(-logf(unif[ue + 1] + 1e-20f) + 1e-20f);
    float z0 = a0 + fcatb[0] + g0;
    float z1 = a1 + fcatb[1] + g1;
    out[(size_t)i * N_NODES + j] = (i == j) ? 0.f : ((z0 >= z1) ? 1.f : 0.f);
  }
}

extern "C" void kernel_launch(void* const* d_in, const int* in_sizes, int n_in,
                              void* d_out, int out_size, void* d_ws, size_t ws_size,
                              hipStream_t stream) {
  const float* nfeat = (const float*)d_in[1];
  const float* w1    = (const float*)d_in[2];
  const float* b1    = (const float*)d_in[3];
  const float* w2    = (const float*)d_in[4];
  const float* b2    = (const float*)d_in[5];
  const float* g1    = (const float*)d_in[6];
  const float* bb1   = (const float*)d_in[7];
  const float* g2    = (const float*)d_in[8];
  const float* bb2   = (const float*)d_in[9];
  const float* g3    = (const float*)d_in[10];
  const float* bb3   = (const float*)d_in[11];
  const float* fcw   = (const float*)d_in[12];
  const float* fcb   = (const float*)d_in[13];
  const float* fow   = (const float*)d_in[14];
  const float* fob   = (const float*)d_in[15];
  const float* fcatw = (const float*)d_in[16];
  const float* fcatb = (const float*)d_in[17];
  const float* unif  = (const float*)d_in[18];
  float* ws  = (float*)d_ws;
  float* out = (float*)d_out;

  dgl_k1_conv1_stats<<<dim3(375), dim3(320), 0, stream>>>(nfeat, w1, b1, ws);
  dgl_k2_fin1<<<dim3(1), dim3(64), 0, stream>>>(g1, bb1, ws);
  dgl_k3_conv2<<<dim3(748, 5), dim3(256), 0, stream>>>(nfeat, w1, b1, w2, b2, ws);
  dgl_k4_fin2<<<dim3(1), dim3(512), 0, stream>>>(g2, bb2, ws);
  dgl_k5_fc<<<dim3(K5CH, 5), dim3(192), 0, stream>>>(fcw, ws);
  dgl_k6_bn3<<<dim3(96), dim3(320), 0, stream>>>(fcb, g3, bb3, ws);
  dgl_k7_proj<<<dim3(307), dim3(192), 0, stream>>>(fow, ws);
  dgl_k8_edge<<<dim3(20, 20), dim3(256), 0, stream>>>(fob, fcatw, fcatb, unif, ws, out);
}

// Round 3
// 328.557 us; speedup vs baseline: 1.1981x; 1.1981x over previous
//
#include <hip/hip_runtime.h>

#define N_NODES 307
#define T_LEN   6000
#define L1      5991
#define L2      5982
#define ED      96
#define FDIM    95712
#define K5CH    187   // K chunks of 512 rows

// ---- workspace layout (float offsets) ----
// consts: [0..7]=s1 [8..15]=t1 [16..31]=s2 [32..47]=t2
static const size_t WS_P1 = 256;                    // conv1 stat partials: 375*16
static const size_t WS_P2 = 8192;                   // conv2 stat partials: 3740*32 = 119680
static const size_t WS_NF = 131072;                 // node_feat: 307*96
static const size_t WS_SP = 196608;                 // s_proj: 307*96
static const size_t WS_RP = 229376;                 // r_proj: 307*96
static const size_t WS_A2 = 262144;                 // a2: 95712*320 = 30,627,840
static const size_t WS_FP = 262144 + 30627840ull;   // fc partials: 187*96*320 = 5,744,640
// total ~= 146.5 MB

// ================= K1: conv1 + relu, channel stats only =================
__global__ __launch_bounds__(320) void dgl_k1_conv1_stats(
    const float* __restrict__ nfeat, const float* __restrict__ w1,
    const float* __restrict__ b1, float* __restrict__ ws) {
  __shared__ float sw1[80], sb1[8];
  __shared__ float sred[5][16];
  int tid = threadIdx.x;
  if (tid < 80) sw1[tid] = w1[tid];
  if (tid < 8)  sb1[tid] = b1[tid];
  __syncthreads();
  int l0 = blockIdx.x * 16;
  int n = tid;
  bool nv = n < N_NODES;
  float xx[26];
#pragma unroll
  for (int j = 0; j < 26; ++j) {
    int t = l0 + j;
    xx[j] = (nv && t < T_LEN) ? nfeat[(size_t)t * N_NODES + n] : 0.f;
  }
  float s[8], q[8];
#pragma unroll
  for (int c = 0; c < 8; ++c) { s[c] = 0.f; q[c] = 0.f; }
#pragma unroll
  for (int dl = 0; dl < 16; ++dl) {
    int l = l0 + dl;
    if (nv && l < L1) {
#pragma unroll
      for (int c = 0; c < 8; ++c) {
        float r = sb1[c];
#pragma unroll
        for (int k = 0; k < 10; ++k) r = fmaf(xx[dl + k], sw1[c * 10 + k], r);
        float z = fmaxf(r, 0.f);
        s[c] += z; q[c] += z * z;
      }
    }
  }
  int wv = tid >> 6, ln = tid & 63;
#pragma unroll
  for (int c = 0; c < 8; ++c) {
    float vs = s[c], vq = q[c];
    for (int o = 32; o; o >>= 1) { vs += __shfl_down(vs, o, 64); vq += __shfl_down(vq, o, 64); }
    if (ln == 0) { sred[wv][c] = vs; sred[wv][8 + c] = vq; }
  }
  __syncthreads();
  if (tid < 16) {
    float t = 0.f;
    for (int w = 0; w < 5; ++w) t += sred[w][tid];
    ws[WS_P1 + (size_t)blockIdx.x * 16 + tid] = t;
  }
}

// ================= K2: finalize bn1 =================
__global__ void dgl_k2_fin1(const float* __restrict__ g1, const float* __restrict__ b1,
                            float* __restrict__ ws) {
  __shared__ double sd[16];
  int tid = threadIdx.x;
  if (tid < 16) {
    double a = 0.0;
    for (int j = 0; j < 375; ++j) a += (double)ws[WS_P1 + (size_t)j * 16 + tid];
    sd[tid] = a;
  }
  __syncthreads();
  if (tid < 8) {
    double cnt = (double)N_NODES * (double)L1;
    double m = sd[tid] / cnt;
    double v = sd[tid + 8] / cnt - m * m;
    double inv = 1.0 / sqrt(v + 1e-5);
    ws[tid]     = (float)((double)g1[tid] * inv);
    ws[8 + tid] = (float)((double)b1[tid] - (double)g1[tid] * inv * m);
  }
}

// ================= K3: fused conv1+bn1 (recompute) -> conv2 + relu -> a2 + stats =================
__global__ __launch_bounds__(256) void dgl_k3_conv2(
    const float* __restrict__ nfeat, const float* __restrict__ w1, const float* __restrict__ b1,
    const float* __restrict__ w2, const float* __restrict__ b2, float* __restrict__ ws) {
  __shared__ float sx[26][64];
  __shared__ float sz[8][17][64];
  __shared__ float sw2[1280], sw1[80], sb1[8], sb2[16], ss1[8], st1[8];
  __shared__ float wpart[4][8];
  int tid = threadIdx.x;
  int lane = tid & 63, g = tid >> 6;
  int l0 = blockIdx.x * 8, n0 = blockIdx.y * 64;
  for (int i = tid; i < 1280; i += 256) sw2[i] = w2[i];
  if (tid < 80) sw1[tid] = w1[tid];
  if (tid < 8)  { sb1[tid] = b1[tid]; ss1[tid] = ws[tid]; st1[tid] = ws[8 + tid]; }
  if (tid < 16) sb2[tid] = b2[tid];
  for (int i = tid; i < 26 * 64; i += 256) {
    int j = i >> 6, l2 = i & 63;
    int t = l0 + j, nn = n0 + l2;
    sx[j][l2] = (t < T_LEN && nn < N_NODES) ? nfeat[(size_t)t * N_NODES + nn] : 0.f;
  }
  __syncthreads();
#pragma unroll
  for (int i = 0; i < 34; ++i) {
    int c = g * 2 + i / 17, lz = i % 17;
    float r = sb1[c];
#pragma unroll
    for (int k = 0; k < 10; ++k) r = fmaf(sx[lz + k][lane], sw1[c * 10 + k], r);
    sz[c][lz][lane] = fmaf(ss1[c], fmaxf(r, 0.f), st1[c]);
  }
  __syncthreads();
  float acc[4][8];
#pragma unroll
  for (int qq = 0; qq < 4; ++qq)
#pragma unroll
    for (int dl = 0; dl < 8; ++dl) acc[qq][dl] = 0.f;
  for (int c = 0; c < 8; ++c) {
    float zr[17];
#pragma unroll
    for (int t = 0; t < 17; ++t) zr[t] = sz[c][t][lane];
#pragma unroll
    for (int k = 0; k < 10; ++k) {
#pragma unroll
      for (int qq = 0; qq < 4; ++qq) {
        float w = sw2[(g * 4 + qq) * 80 + c * 10 + k];
#pragma unroll
        for (int dl = 0; dl < 8; ++dl) acc[qq][dl] = fmaf(zr[dl + k], w, acc[qq][dl]);
      }
    }
  }
  int n = n0 + lane;
  bool nv = n < N_NODES;
  float s4[4] = {0.f, 0.f, 0.f, 0.f}, q4[4] = {0.f, 0.f, 0.f, 0.f};
#pragma unroll
  for (int qq = 0; qq < 4; ++qq) {
    int c2 = g * 4 + qq;
#pragma unroll
    for (int dl = 0; dl < 8; ++dl) {
      int l = l0 + dl;
      float v = 0.f;
      if (nv && l < L2) v = fmaxf(acc[qq][dl] + sb2[c2], 0.f);
      if (l < L2) ws[WS_A2 + ((size_t)c2 * L2 + l) * 320 + n] = v;
      s4[qq] += v; q4[qq] += v * v;
    }
  }
#pragma unroll
  for (int qq = 0; qq < 4; ++qq) {
    float vs = s4[qq], vq = q4[qq];
    for (int o = 32; o; o >>= 1) { vs += __shfl_down(vs, o, 64); vq += __shfl_down(vq, o, 64); }
    if (lane == 0) { wpart[g][qq] = vs; wpart[g][4 + qq] = vq; }
  }
  __syncthreads();
  if (tid < 32) {
    int c2 = tid & 15; bool isq = tid >= 16;
    float v = wpart[c2 >> 2][(isq ? 4 : 0) + (c2 & 3)];
    ws[WS_P2 + ((size_t)blockIdx.y * gridDim.x + blockIdx.x) * 32 + tid] = v;
  }
}

// ================= K4: finalize bn2 =================
__global__ __launch_bounds__(512) void dgl_k4_fin2(const float* __restrict__ g2,
                                                   const float* __restrict__ b2,
                                                   float* __restrict__ ws) {
  __shared__ double dd[32][17];
  int tid = threadIdx.x;
  int v = tid >> 4, p = tid & 15;
  double a = 0.0;
  for (int j = p; j < 3740; j += 16) a += (double)ws[WS_P2 + (size_t)j * 32 + v];
  dd[v][p] = a;
  __syncthreads();
  if (tid < 32) {
    double s = 0.0;
    for (int pp = 0; pp < 16; ++pp) s += dd[tid][pp];
    dd[tid][16] = s;
  }
  __syncthreads();
  if (tid < 16) {
    double cnt = (double)N_NODES * (double)L2;
    double m = dd[tid][16] / cnt;
    double var = dd[tid + 16][16] / cnt - m * m;
    double inv = 1.0 / sqrt(var + 1e-5);
    ws[16 + tid] = (float)((double)g2[tid] * inv);
    ws[32 + tid] = (float)((double)b2[tid] - (double)g2[tid] * inv * m);
  }
}

// ================= K5: split-K GEMM, single-buffer high-TLP, 512 rows x 32 cols per block =================
__global__ __launch_bounds__(192) void dgl_k5_fc(const float* __restrict__ fcw,
                                                 float* __restrict__ ws) {
  __shared__ float As[16][36];
  __shared__ float Bs[16][100];
  __shared__ float s2s[16], t2s[16];
  int tid = threadIdx.x;
  if (tid < 16) { s2s[tid] = ws[16 + tid]; t2s[tid] = ws[32 + tid]; }
  __syncthreads();
  int ch = blockIdx.x;
  int n0 = blockIdx.y * 32;
  int fb0 = ch * 512;
  const float* a2 = ws + WS_A2;
  int tn = tid / 24;   // 0..7  -> 4 n-cols each
  int te = tid % 24;   // 0..23 -> 4 e-cols each
  float acc[4][4];
#pragma unroll
  for (int i = 0; i < 4; ++i)
#pragma unroll
    for (int j = 0; j < 4; ++j) acc[i][j] = 0.f;

  int ar = tid >> 3, ac = tid & 7;   // A staging: tid<128 -> row 0..15, col4 0..7
  for (int ks = 0; ks < 32; ++ks) {
    int fbase = fb0 + ks * 16;
    if (tid < 128) {
      int f = fbase + ar;
      float4 v = make_float4(0.f, 0.f, 0.f, 0.f);
      float sc = 0.f, sh = 0.f;
      if (f < FDIM) {
        v = *(const float4*)(a2 + (size_t)f * 320 + n0 + ac * 4);
        int cc = f / L2;
        sc = s2s[cc]; sh = t2s[cc];
      }
      float4 o;
      o.x = fmaf(sc, v.x, sh); o.y = fmaf(sc, v.y, sh);
      o.z = fmaf(sc, v.z, sh); o.w = fmaf(sc, v.w, sh);
      *(float4*)(&As[ar][ac * 4]) = o;
    }
#pragma unroll
    for (int i = tid; i < 384; i += 192) {
      int r = i / 24, c4 = i % 24;
      int f = fbase + r;
      float4 wv = (f < FDIM) ? *(const float4*)(fcw + (size_t)f * 96 + c4 * 4)
                             : make_float4(0.f, 0.f, 0.f, 0.f);
      *(float4*)(&Bs[r][c4 * 4]) = wv;
    }
    __syncthreads();
#pragma unroll
    for (int kk = 0; kk < 16; ++kk) {
      float a[4], b[4];
      *(float4*)(a) = *(float4*)(&As[kk][tn * 4]);
      *(float4*)(b) = *(float4*)(&Bs[kk][te * 4]);
#pragma unroll
      for (int i = 0; i < 4; ++i)
#pragma unroll
        for (int j = 0; j < 4; ++j) acc[i][j] = fmaf(a[i], b[j], acc[i][j]);
    }
    __syncthreads();
  }
  float* fp = ws + WS_FP;
#pragma unroll
  for (int j = 0; j < 4; ++j) {
    int e = te * 4 + j;
    size_t base = ((size_t)ch * 96 + e) * 320 + n0 + tn * 4;
    float4 o = {acc[0][j], acc[1][j], acc[2][j], acc[3][j]};
    *(float4*)(fp + base) = o;
  }
}

// ================= K6: chunk-reduce (fp64) + fc bias + relu + bn3 -> node_feat =================
__global__ __launch_bounds__(320) void dgl_k6_bn3(const float* __restrict__ fcb,
                                                  const float* __restrict__ g3,
                                                  const float* __restrict__ b3,
                                                  float* __restrict__ ws) {
  int e = blockIdx.x, tid = threadIdx.x;
  const float* fp = ws + WS_FP;
  double a = 0.0;
  for (int ch = 0; ch < K5CH; ++ch) a += (double)fp[((size_t)ch * 96 + e) * 320 + tid];
  float x = fmaxf((float)a + fcb[e], 0.f);
  if (tid >= N_NODES) x = 0.f;
  double s = (double)x, q = (double)x * (double)x;
  __shared__ double rs[5], rq[5];
  __shared__ float mb[2];
  int wv = tid >> 6, ln = tid & 63;
  for (int o = 32; o; o >>= 1) { s += __shfl_down(s, o, 64); q += __shfl_down(q, o, 64); }
  if (ln == 0) { rs[wv] = s; rq[wv] = q; }
  __syncthreads();
  if (tid == 0) {
    double S = 0.0, Q = 0.0;
    for (int w = 0; w < 5; ++w) { S += rs[w]; Q += rq[w]; }
    double m = S / (double)N_NODES;
    double var = Q / (double)N_NODES - m * m;
    mb[0] = (float)m; mb[1] = (float)(1.0 / sqrt(var + 1e-5));
  }
  __syncthreads();
  if (tid < N_NODES)
    ws[WS_NF + (size_t)tid * 96 + e] = g3[e] * (x - mb[0]) * mb[1] + b3[e];
}

// ================= K7: s_proj / r_proj =================
__global__ __launch_bounds__(192) void dgl_k7_proj(const float* __restrict__ fow,
                                                   float* __restrict__ ws) {
  __shared__ float sh[96];
  int nI = blockIdx.x, tid = threadIdx.x;
  if (tid < 96) sh[tid] = ws[WS_NF + (size_t)nI * 96 + tid];
  __syncthreads();
  int col = tid % 96, half = tid / 96;
  float a = 0.f;
#pragma unroll 8
  for (int d = 0; d < 96; ++d) a = fmaf(sh[d], fow[(size_t)(half * 96 + d) * 96 + col], a);
  ws[(half ? WS_RP : WS_SP) + (size_t)nI * 96 + col] = a;
}

// ================= K8: edge relu + logits + gumbel + hard argmax -> adj =================
__global__ __launch_bounds__(256) void dgl_k8_edge(const float* __restrict__ fob,
                                                   const float* __restrict__ fcatw,
                                                   const float* __restrict__ fcatb,
                                                   const float* __restrict__ unif,
                                                   const float* __restrict__ ws,
                                                   float* __restrict__ out) {
  __shared__ float rp[16][100], sp[16][100], bb[96], wa[96], wb[96];
  int tid = threadIdx.x;
  int i0 = blockIdx.y * 16, j0 = blockIdx.x * 16;
  for (int idx = tid; idx < 16 * 96; idx += 256) {
    int r = idx / 96, e = idx % 96;
    int ii = i0 + r, jj = j0 + r;
    rp[r][e] = (ii < N_NODES) ? ws[WS_RP + (size_t)ii * 96 + e] : 0.f;
    sp[r][e] = (jj < N_NODES) ? ws[WS_SP + (size_t)jj * 96 + e] : 0.f;
  }
  if (tid < 96) { bb[tid] = fob[tid]; wa[tid] = fcatw[2 * tid]; wb[tid] = fcatw[2 * tid + 1]; }
  __syncthreads();
  int il = tid >> 4, jl = tid & 15;
  int i = i0 + il, j = j0 + jl;
  float a0 = 0.f, a1 = 0.f;
#pragma unroll 4
  for (int e = 0; e < 96; ++e) {
    float ef = fmaxf(rp[il][e] + sp[jl][e] + bb[e], 0.f);
    a0 = fmaf(ef, wa[e], a0);
    a1 = fmaf(ef, wb[e], a1);
  }
  if (i < N_NODES && j < N_NODES) {
    size_t ue = ((size_t)i * N_NODES + j) * 2;
    float g0 = -logf(-logf(unif[ue] + 1e-20f) + 1e-20f);
    float g1 = -logf(-logf(unif[ue + 1] + 1e-20f) + 1e-20f);
    float z0 = a0 + fcatb[0] + g0;
    float z1 = a1 + fcatb[1] + g1;
    out[(size_t)i * N_NODES + j] = (i == j) ? 0.f : ((z0 >= z1) ? 1.f : 0.f);
  }
}

extern "C" void kernel_launch(void* const* d_in, const int* in_sizes, int n_in,
                              void* d_out, int out_size, void* d_ws, size_t ws_size,
                              hipStream_t stream) {
  const float* nfeat = (const float*)d_in[1];
  const float* w1    = (const float*)d_in[2];
  const float* b1    = (const float*)d_in[3];
  const float* w2    = (const float*)d_in[4];
  const float* b2    = (const float*)d_in[5];
  const float* g1    = (const float*)d_in[6];
  const float* bb1   = (const float*)d_in[7];
  const float* g2    = (const float*)d_in[8];
  const float* bb2   = (const float*)d_in[9];
  const float* g3    = (const float*)d_in[10];
  const float* bb3   = (const float*)d_in[11];
  const float* fcw   = (const float*)d_in[12];
  const float* fcb   = (const float*)d_in[13];
  const float* fow   = (const float*)d_in[14];
  const float* fob   = (const float*)d_in[15];
  const float* fcatw = (const float*)d_in[16];
  const float* fcatb = (const float*)d_in[17];
  const float* unif  = (const float*)d_in[18];
  float* ws  = (float*)d_ws;
  float* out = (float*)d_out;

  dgl_k1_conv1_stats<<<dim3(375), dim3(320), 0, stream>>>(nfeat, w1, b1, ws);
  dgl_k2_fin1<<<dim3(1), dim3(64), 0, stream>>>(g1, bb1, ws);
  dgl_k3_conv2<<<dim3(748, 5), dim3(256), 0, stream>>>(nfeat, w1, b1, w2, b2, ws);
  dgl_k4_fin2<<<dim3(1), dim3(512), 0, stream>>>(g2, bb2, ws);
  dgl_k5_fc<<<dim3(K5CH, 10), dim3(192), 0, stream>>>(fcw, ws);
  dgl_k6_bn3<<<dim3(96), dim3(320), 0, stream>>>(fcb, g3, bb3, ws);
  dgl_k7_proj<<<dim3(307), dim3(192), 0, stream>>>(fow, ws);
  dgl_k8_edge<<<dim3(20, 20), dim3(256), 0, stream>>>(fob, fcatw, fcatb, unif, ws, out);
}